// Round 2
// baseline (104.852 us; speedup 1.0000x reference)
//
#include <hip/hip_runtime.h>

// Flanger: v[n] = x[n] + 0.5*y[n], y[n] = (1-g)*v[n-da] + g*v[n-(k+1)]
// where delay = 441*mod[n], k = floor(delay), g = frac, da = (k==0 ? 441 : k).
// Delays depend only on mod_sig (not data) -> linear recurrence with
// contraction factor exactly 0.5 -> Jacobi iteration, each sweep fully
// parallel over 16 channels x 32768 samples. 12 sweeps: worst-case error
// 0.7*4.7*2^-12 ~ 8e-4 << 0.114 threshold.
//
// Layout: x, mod, V all [16][32768] flat (channel-major, matches [8,2,32768]).

#define NSAMP 32768
#define NCH   16
#define TOTAL (NSAMP * NCH)
#define DLY   441

__global__ __launch_bounds__(256) void flanger_sweep(
    const float* __restrict__ x, const float* __restrict__ mod,
    const float* __restrict__ Vold, float* __restrict__ Vnew,
    float wy)   // Vnew = x + wy * y;  wy=0.5 for sweeps, wy=0.7 for final mix
{
    int idx = blockIdx.x * 256 + threadIdx.x;      // 0..TOTAL-1
    int n   = idx & (NSAMP - 1);                   // sample index within channel
    int base = idx - n;                            // channel base offset

    float m     = mod[idx];
    float delay = 441.0f * m;                      // in [0, 441)
    float kf    = floorf(delay);
    float g     = delay - kf;                      // frac part
    int   k     = (int)kf;

    // weight (1-g) at distance da; weight g at distance k+1
    int da = (k == 0) ? DLY : k;
    int db = k + 1;
    int ia = n - da;
    int ib = n - db;

    float va = (ia >= 0) ? Vold[base + ia] : 0.0f;
    float vb = (ib >= 0) ? Vold[base + ib] : 0.0f;
    float y  = (1.0f - g) * va + g * vb;

    Vnew[idx] = x[idx] + wy * y;
}

extern "C" void kernel_launch(void* const* d_in, const int* in_sizes, int n_in,
                              void* d_out, int out_size, void* d_ws, size_t ws_size,
                              hipStream_t stream) {
    const float* x   = (const float*)d_in[0];
    const float* mod = (const float*)d_in[1];
    float*       out = (float*)d_out;

    float* VA = (float*)d_ws;          // 2 MB
    float* VB = VA + TOTAL;            // 2 MB  (ws needs >= 4 MB)

    dim3 grid(TOTAL / 256), block(256);

    const float* src = x;              // V^0 = x  (y=0 start)
    float*       dst = VA;
    for (int it = 0; it < 12; ++it) {
        flanger_sweep<<<grid, block, 0, stream>>>(x, mod, src, dst, 0.5f);
        src = dst;
        dst = (dst == VA) ? VB : VA;
    }
    // Final: out = x + 0.7 * y(V^12)
    flanger_sweep<<<grid, block, 0, stream>>>(x, mod, src, out, 0.7f);
}

// Round 3
// 75.534 us; speedup vs baseline: 1.3881x; 1.3881x over previous
//
#include <hip/hip_runtime.h>

// Fused flanger via chunk-local Jacobi relaxation in LDS.
//
// v[n] = x[n] + 0.5*((1-g)*v[n-da] + g*v[n-(k+1)]),  delay=441*mod[n],
// k=floor(delay), g=frac, da=(k==0?441:k).  out = x + 0.7*y(V).
// Influence decays 0.5 per hop, each hop <=442 samples => a chunk of 2048
// outputs needs only a 5888-sample halo (13 hops) of locally-relaxed history.
// 256 blocks (16 channels x 16 chunks), no inter-block communication.
//
// Shrinking active window: iteration i only must update n >= HALO-(S-i+1)*442;
// the taps of that region land exactly on the previous iteration's active
// region, so the shrink is exact (no extra error).

#define NSAMP  32768
#define DLY    441
#define CHUNK  2048
#define HALO   5888              // 23*256; floor(5888/442) = 13 hops
#define WLEN   (CHUNK + HALO)    // 7936 = 31*256
#define JN     (WLEN / 256)      // 31 samples per thread
#define JKEEP  (HALO / 256)      // 23: first kept j-slot
#define SWEEPS 13
#define ZSLOT  WLEN              // LDS slot that is always 0.0f

__global__ __launch_bounds__(256, 1) void flanger_fused(
    const float* __restrict__ x, const float* __restrict__ mod,
    float* __restrict__ out)
{
    __shared__ float V[2][WLEN + 1];

    const int t   = threadIdx.x;
    const int blk = blockIdx.x;
    const int ch  = blk >> 4;          // 16 chunks per channel
    const int ck  = blk & 15;
    const int g0  = ck * CHUNK;        // first kept global sample
    const int wg0 = g0 - HALO;         // window start (may be negative)

    const float* xc = x   + ch * NSAMP;
    const float* mc = mod + ch * NSAMP;

    // Per-thread state, compile-time indexed (stays in VGPRs).
    float xr[JN], gr[JN];
    int   ta[JN], tb[JN];

    #pragma unroll
    for (int j = 0; j < JN; ++j) {
        const int nl = t + 256 * j;    // local window index
        const int gn = wg0 + nl;       // global sample index (< NSAMP always)
        float xv = 0.0f, m = 0.0f;
        if (gn >= 0) { xv = xc[gn]; m = mc[gn]; }
        xr[j] = xv;
        const float delay = 441.0f * m;
        const float kf    = floorf(delay);
        gr[j] = delay - kf;
        const int k  = (int)kf;
        const int da = (k == 0) ? DLY : k;   // weight (1-g) tap distance
        const int db = k + 1;                // weight g tap distance
        int a = nl - da; if (a < 0) a = ZSLOT;
        int b = nl - db; if (b < 0) b = ZSLOT;
        ta[j] = a;
        tb[j] = b;
        V[0][nl] = xv;                 // V^0 = x
    }
    if (t == 0) { V[0][ZSLOT] = 0.0f; V[1][ZSLOT] = 0.0f; }
    __syncthreads();

    // Jacobi sweeps, double-buffered (1 barrier per sweep, deterministic).
    int cur = 0;
    for (int i = 1; i <= SWEEPS; ++i) {
        const int lo   = HALO - (SWEEPS - i + 1) * 442;
        const int jmin = (lo <= 0) ? 0 : (lo >> 8);
        const float* __restrict__ Vo = V[cur];
        float* __restrict__       Vn = V[cur ^ 1];
        #pragma unroll
        for (int j = 0; j < JN; ++j) {
            if (j >= jmin) {
                const float va = Vo[ta[j]];
                const float vb = Vo[tb[j]];
                const float y  = (1.0f - gr[j]) * va + gr[j] * vb;
                Vn[t + 256 * j] = xr[j] + 0.5f * y;
            }
        }
        cur ^= 1;
        __syncthreads();
    }

    // Output pass: out = x + 0.7 * y(V^S), kept region only.
    const float* __restrict__ Vf = V[cur];
    float* o = out + ch * NSAMP + g0;
    #pragma unroll
    for (int j = JKEEP; j < JN; ++j) {
        const float va = Vf[ta[j]];
        const float vb = Vf[tb[j]];
        const float y  = (1.0f - gr[j]) * va + gr[j] * vb;
        o[t + 256 * (j - JKEEP)] = xr[j] + 0.7f * y;
    }
}

extern "C" void kernel_launch(void* const* d_in, const int* in_sizes, int n_in,
                              void* d_out, int out_size, void* d_ws, size_t ws_size,
                              hipStream_t stream) {
    const float* x   = (const float*)d_in[0];
    const float* mod = (const float*)d_in[1];
    float*       out = (float*)d_out;

    dim3 grid(256), block(256);   // 16 channels x 16 chunks
    flanger_fused<<<grid, block, 0, stream>>>(x, mod, out);
}

// Round 4
// 72.025 us; speedup vs baseline: 1.4558x; 1.0487x over previous
//
#include <hip/hip_runtime.h>

// Fused flanger via chunk-local Jacobi relaxation in LDS.
//
// v[n] = x[n] + 0.5*((1-g)*v[n-da] + g*v[n-(k+1)]),  delay=441*mod[n],
// k=floor(delay), g=frac, da=(k==0?441:k).  out = x + 0.7*y(V).
// Influence decays 0.5 per hop, each hop <=442 samples => a chunk of CHUNK
// outputs needs only a (SWEEPS hops)*442 halo of locally-relaxed history.
// 512 blocks (16 channels x 32 chunks) -> 2 blocks/CU for latency hiding.
//
// Shrinking active window: sweep i only updates n >= HALO-(S-i+1)*442; the
// taps of that region land exactly on the previous sweep's active region
// (lo_i - 442 == lo_{i-1}), so the shrink is exact.

#define NSAMP  32768
#define DLY    441
#define CHUNK  1024
#define HALO   4608              // 18*256; 10 hops * 442 = 4420 <= 4608
#define WLEN   (CHUNK + HALO)    // 5632 = 22*256
#define JN     (WLEN / 256)      // 22 samples per thread
#define JKEEP  (HALO / 256)      // 18: first kept j-slot
#define SWEEPS 10
#define ZSLOT  WLEN              // LDS slot that is always 0.0f

__global__ __launch_bounds__(256, 2) void flanger_fused(
    const float* __restrict__ x, const float* __restrict__ mod,
    float* __restrict__ out)
{
    __shared__ float V[2][WLEN + 1];   // 45 KB -> 2 blocks/CU

    const int t   = threadIdx.x;
    const int blk = blockIdx.x;
    const int ch  = blk >> 5;          // 32 chunks per channel
    const int ck  = blk & 31;
    const int g0  = ck * CHUNK;        // first kept global sample
    const int wg0 = g0 - HALO;         // window start (may be negative)

    const float* xc = x   + ch * NSAMP;
    const float* mc = mod + ch * NSAMP;

    // Per-thread state, compile-time indexed (stays in VGPRs).
    float xr[JN], gr[JN];
    int   ta[JN], tb[JN];

    #pragma unroll
    for (int j = 0; j < JN; ++j) {
        const int nl = t + 256 * j;    // local window index
        const int gn = wg0 + nl;       // global sample index (< NSAMP always)
        float xv = 0.0f, m = 0.0f;
        if (gn >= 0) { xv = xc[gn]; m = mc[gn]; }
        xr[j] = xv;
        const float delay = 441.0f * m;
        const float kf    = floorf(delay);
        gr[j] = delay - kf;
        const int k  = (int)kf;
        const int da = (k == 0) ? DLY : k;   // weight (1-g) tap distance
        const int db = k + 1;                // weight g tap distance
        int a = nl - da; if (a < 0) a = ZSLOT;
        int b = nl - db; if (b < 0) b = ZSLOT;
        ta[j] = a;
        tb[j] = b;
        V[0][nl] = xv;                 // V^0 = x
    }
    if (t == 0) { V[0][ZSLOT] = 0.0f; V[1][ZSLOT] = 0.0f; }
    __syncthreads();

    // Jacobi sweeps, double-buffered (1 barrier per sweep, deterministic).
    int cur = 0;
    for (int i = 1; i <= SWEEPS; ++i) {
        const int lo   = HALO - (SWEEPS - i + 1) * 442;
        const int jmin = (lo <= 0) ? 0 : (lo >> 8);
        const float* __restrict__ Vo = V[cur];
        float* __restrict__       Vn = V[cur ^ 1];
        #pragma unroll
        for (int j = 0; j < JN; ++j) {
            if (j >= jmin) {
                const float va = Vo[ta[j]];
                const float vb = Vo[tb[j]];
                const float y  = (1.0f - gr[j]) * va + gr[j] * vb;
                Vn[t + 256 * j] = xr[j] + 0.5f * y;
            }
        }
        cur ^= 1;
        __syncthreads();
    }

    // Output pass: out = x + 0.7 * y(V^S), kept region only.
    const float* __restrict__ Vf = V[cur];
    float* o = out + ch * NSAMP + g0;
    #pragma unroll
    for (int j = JKEEP; j < JN; ++j) {
        const float va = Vf[ta[j]];
        const float vb = Vf[tb[j]];
        const float y  = (1.0f - gr[j]) * va + gr[j] * vb;
        o[t + 256 * (j - JKEEP)] = xr[j] + 0.7f * y;
    }
}

extern "C" void kernel_launch(void* const* d_in, const int* in_sizes, int n_in,
                              void* d_out, int out_size, void* d_ws, size_t ws_size,
                              hipStream_t stream) {
    const float* x   = (const float*)d_in[0];
    const float* mod = (const float*)d_in[1];
    float*       out = (float*)d_out;

    dim3 grid(512), block(256);   // 16 channels x 32 chunks
    flanger_fused<<<grid, block, 0, stream>>>(x, mod, out);
}